// Round 9
// baseline (175.517 us; speedup 1.0000x reference)
//
#include <hip/hip_runtime.h>
#include <math.h>

#define SQRTC  0.94868329805051381f       // sqrt(0.9)
#define MAXN   (0.996f/SQRTC)             // (1-PROJ_EPS)/sqrt(c)
#define OME_CLIP (1.0f - 0.996f*0.996f)   // 1 - c*maxnorm^2
#define TWO_OVER_SQRTC 2.1081851067789197f

typedef unsigned short u16;
typedef __attribute__((ext_vector_type(8))) short bf8;   // 8 bf16 (4 VGPRs)
typedef __attribute__((ext_vector_type(4))) float f4;    // MFMA C/D

__device__ __forceinline__ u16 f2bf(float f){
    union { float f; unsigned int i; } v; v.f = f;
    unsigned int x = v.i;
    unsigned int lsb = (x >> 16) & 1u;
    x += 0x7fffu + lsb;
    return (u16)(x >> 16);
}
__device__ __forceinline__ float bf2f(u16 u){
    union { unsigned int i; float f; } v; v.i = ((unsigned int)u) << 16; return v.f;
}

__device__ __forceinline__ float pdist_stable(float ome_x, float ome_y, float t){
    float u = 1.0f - ome_x, v = 1.0f - ome_y;   // c*x2, c*y2
    float den = fmaxf(1.0f - 1.8f*t + u*v, 1e-15f);
    float q = ome_x*ome_y/den;                   // = 1 - z^2
    q = fminf(fmaxf(q, 2.0e-7f), 1.0f);
    float z = sqrtf(fmaxf(1.0f - q, 0.0f));
    float at = 0.5f * logf((1.0f+z)*(1.0f+z)/q); // atanh(z)
    return TWO_OVER_SQRTC * at;
}

__device__ __forceinline__ void expmap_scale_ome(float sum, float* fout, float* omeout){
    float nraw = sqrtf(fmaxf(sum, 1e-30f));
    float n = fmaxf(nraw, 1e-15f);
    float sn = SQRTC*n;
    float th = tanhf(sn);
    float factor = th/sn;
    float gn = factor*nraw;
    if (gn > MAXN){ *fout = factor*(MAXN/gn); *omeout = OME_CLIP; }
    else { *fout = factor; *omeout = fmaxf((1.0f-th)*(1.0f+th), 1e-12f); }
}

// D1: blocks 0..1007 rowmax; 1008..3183 prep (text cvt + weight transposes).
__global__ __launch_bounds__(256)
void k_stage1(const float* __restrict__ summ, const float* __restrict__ cand,
              const float* __restrict__ text,
              const float* __restrict__ w1, const float* __restrict__ w2,
              const float* __restrict__ wp,
              float* __restrict__ smax, float* __restrict__ cmax,
              u16* __restrict__ textb, u16* __restrict__ w1t,
              u16* __restrict__ w2t, u16* __restrict__ wpt)
{
    __shared__ float shm[1056];
    int bx = blockIdx.x;
    int t = threadIdx.x;
    if (bx < 1008){
        int row = bx / 12, ht = bx - row*12;
        int lane = t & 63, lg = t >> 6;
        int h = ht*64 + lane;
        const float* in = (row < 4) ? (summ + (long long)row*128*768)
                                    : (cand + (long long)(row-4)*128*768);
        const float* p = in + (long long)(lg*32)*768 + h;
        float m = -INFINITY;
        #pragma unroll 8
        for (int l = 0; l < 32; l++) m = fmaxf(m, p[l*768]);
        shm[t] = m; __syncthreads();
        if (t < 64){
            float mm = fmaxf(fmaxf(shm[t], shm[t+64]), fmaxf(shm[t+128], shm[t+192]));
            if (row < 4) smax[row*768 + h] = mm;
            else cmax[(row-4)*768 + h] = mm;
        }
        return;
    }
    int pb = bx - 1008;
    if (pb < 768){
        int base = pb*2048 + t*8;
        float4 a = *(const float4*)(text + base);
        float4 b = *(const float4*)(text + base + 4);
        *(ushort4*)(textb + base)     = make_ushort4(f2bf(a.x), f2bf(a.y), f2bf(a.z), f2bf(a.w));
        *(ushort4*)(textb + base + 4) = make_ushort4(f2bf(b.x), f2bf(b.y), f2bf(b.z), f2bf(b.w));
        return;
    }
    int j = pb - 768;
    const float* in; u16* outp; int K;
    if (j < 384){ in = w1; outp = w1t; K = 768; }
    else if (j < 1152){ j -= 384; in = w2; outp = w2t; K = 1536; }
    else { j -= 1152; in = wp; outp = wpt; K = 512; }
    const int N = 512, ntile = N/32;
    int k0 = (j/ntile)*32, n0 = (j - (j/ntile)*ntile)*32;
    int tx = t & 31, ty = t >> 5;
    #pragma unroll
    for (int i = 0; i < 4; i++)
        shm[(ty*4+i)*33 + tx] = in[(long long)(k0 + ty*4 + i)*N + n0 + tx];
    __syncthreads();
    #pragma unroll
    for (int i = 0; i < 4; i++)
        outp[(long long)(n0 + ty*4 + i)*K + k0 + tx] = f2bf(shm[tx*33 + ty*4+i]);
}

// D2: blocks 0..255 conv MFMA (BM=128,BN=64,BK=32); 256..959 emb_gemv.
__global__ __launch_bounds__(256)
void k_stage2(const u16* __restrict__ textb,
              const u16* __restrict__ w1t, const u16* __restrict__ w2t,
              const float* __restrict__ cb1, const float* __restrict__ cb2,
              const float* __restrict__ text,
              const float* __restrict__ smax, const float* __restrict__ cmax,
              const float* __restrict__ W_d, const float* __restrict__ W_s,
              const float* __restrict__ W_c,
              u16* __restrict__ gram, float* __restrict__ emb_all)
{
    __shared__ char smem[12288];
    int bx = blockIdx.x;
    int t = threadIdx.x;
    if (bx < 256){
        // ---- conv MFMA: xx = m-tile(16) x job(2); yy = n-tile(8) ----
        u16 (*As)[32] = (u16(*)[32])smem;          // [128][32] 8 KB
        u16 (*Bs)[32] = (u16(*)[32])(smem + 8192); // [64][32]  4 KB
        int xx = bx & 31, yy = bx >> 5;
        int job = xx & 1;
        int m0 = (xx >> 1) * 128;
        int n0 = yy * 64;
        int K   = job ? 1536 : 768;
        int M   = job ? 2036 : 2040;
        int rpb = job ? 509 : 510;
        int ob  = job ? 510 : 0;
        const u16* Bt = job ? w2t : w1t;
        const float* bias = job ? cb2 : cb1;
        int sra = t >> 1, ska = (t & 1) << 4;   // A: 128 rows x 2 16-u16 segs
        int srb = t >> 2, skb = (t & 3) << 3;   // B: 64 rows x 4 8-u16 segs
        const u16* Arow = nullptr;
        { int gm = m0 + sra; if (gm < M){ int b = gm/rpb, l = gm - b*rpb;
            Arow = textb + (long long)b*393216 + (long long)(l+1)*768; } }
        const u16* Brow = Bt + (long long)(n0 + srb)*K;
        int lane = t & 63, wv = t >> 6;
        int fm = lane & 15, fq = lane >> 4;
        f4 acc[2][4] = {};
        for (int k0 = 0; k0 < K; k0 += 32){
            bf8 a0 = {}, a1 = {};
            if (Arow){ a0 = *(const bf8*)(Arow + k0 + ska);
                       a1 = *(const bf8*)(Arow + k0 + ska + 8); }
            bf8 bv = *(const bf8*)(Brow + k0 + skb);
            *(bf8*)&As[sra][ska]     = a0;
            *(bf8*)&As[sra][ska + 8] = a1;
            *(bf8*)&Bs[srb][skb]     = bv;
            __syncthreads();
            bf8 af0 = *(const bf8*)&As[wv*32      + fm][fq*8];
            bf8 af1 = *(const bf8*)&As[wv*32 + 16 + fm][fq*8];
            bf8 b0 = *(const bf8*)&Bs[ 0+fm][fq*8];
            bf8 b1 = *(const bf8*)&Bs[16+fm][fq*8];
            bf8 b2 = *(const bf8*)&Bs[32+fm][fq*8];
            bf8 b3 = *(const bf8*)&Bs[48+fm][fq*8];
            acc[0][0] = __builtin_amdgcn_mfma_f32_16x16x32_bf16(af0, b0, acc[0][0], 0,0,0);
            acc[0][1] = __builtin_amdgcn_mfma_f32_16x16x32_bf16(af0, b1, acc[0][1], 0,0,0);
            acc[0][2] = __builtin_amdgcn_mfma_f32_16x16x32_bf16(af0, b2, acc[0][2], 0,0,0);
            acc[0][3] = __builtin_amdgcn_mfma_f32_16x16x32_bf16(af0, b3, acc[0][3], 0,0,0);
            acc[1][0] = __builtin_amdgcn_mfma_f32_16x16x32_bf16(af1, b0, acc[1][0], 0,0,0);
            acc[1][1] = __builtin_amdgcn_mfma_f32_16x16x32_bf16(af1, b1, acc[1][1], 0,0,0);
            acc[1][2] = __builtin_amdgcn_mfma_f32_16x16x32_bf16(af1, b2, acc[1][2], 0,0,0);
            acc[1][3] = __builtin_amdgcn_mfma_f32_16x16x32_bf16(af1, b3, acc[1][3], 0,0,0);
            __syncthreads();
        }
        float bvv[4];
        #pragma unroll
        for (int n = 0; n < 4; n++) bvv[n] = bias[n0 + n*16 + fm];
        #pragma unroll
        for (int g = 0; g < 2; g++){
            #pragma unroll
            for (int i = 0; i < 4; i++){
                int row = m0 + wv*32 + g*16 + fq*4 + i;
                if (row >= M) continue;
                int b = row/rpb, l = row - b*rpb;
                long long orow = (long long)b*1019 + ob + l;
                u16* gp = gram + orow*512 + n0 + fm;
                gp[ 0] = f2bf(fmaxf(acc[g][0][i] + bvv[0], 0.f));
                gp[16] = f2bf(fmaxf(acc[g][1][i] + bvv[1], 0.f));
                gp[32] = f2bf(fmaxf(acc[g][2][i] + bvv[2], 0.f));
                gp[48] = f2bf(fmaxf(acc[g][3][i] + bvv[3], 0.f));
            }
        }
        return;
    }
    // ---- emb_gemv: 88 rows x 8 col-tiles ----
    {
        int eb = bx - 256;
        int row = eb >> 3, nt = eb & 7;
        float* a   = (float*)smem;          // 768 floats
        float* red = (float*)smem + 768;    // 256 floats
        const float* A; const float* W;
        if (row < 4){ A = text + (long long)row*512*768; W = W_d; }
        else if (row < 8){ A = smax + (long long)(row-4)*768; W = W_s; }
        else { A = cmax + (long long)(row-8)*768; W = W_c; }
        for (int k = t; k < 768; k += 256) a[k] = A[k];
        __syncthreads();
        int lane = t & 63, kg = t >> 6;
        int col = nt*64 + lane;
        const float* Wp = W + (long long)(kg*192)*512 + col;
        float acc = 0.f;
        #pragma unroll 8
        for (int k = 0; k < 192; k++) acc += a[kg*192 + k] * Wp[k*512];
        red[t] = acc; __syncthreads();
        if (t < 64) emb_all[(long long)row*512 + col] = red[t] + red[t+64] + red[t+128] + red[t+192];
    }
}

// D3: blocks 0..255 W_p MFMA (BM=128,BN=64); 256..343 expmap88.
__global__ __launch_bounds__(256)
void k_stage3(const u16* __restrict__ gram, const u16* __restrict__ wpt,
              u16* __restrict__ dwe_b,
              float* __restrict__ emb_all, float* __restrict__ ome_all)
{
    __shared__ char smem[12288];
    int bx = blockIdx.x;
    int t = threadIdx.x;
    if (bx < 256){
        u16 (*As)[32] = (u16(*)[32])smem;
        u16 (*Bs)[32] = (u16(*)[32])(smem + 8192);
        const int K = 512, M = 4076;
        int m0 = (bx >> 3) * 128;
        int n0 = (bx & 7) * 64;
        int sra = t >> 1, ska = (t & 1) << 4;
        int srb = t >> 2, skb = (t & 3) << 3;
        const u16* Arow = (m0 + sra < M) ? (gram + (long long)(m0 + sra)*512) : nullptr;
        const u16* Brow = wpt + (long long)(n0 + srb)*K;
        int lane = t & 63, wv = t >> 6;
        int fm = lane & 15, fq = lane >> 4;
        f4 acc[2][4] = {};
        for (int k0 = 0; k0 < K; k0 += 32){
            bf8 a0 = {}, a1 = {};
            if (Arow){ a0 = *(const bf8*)(Arow + k0 + ska);
                       a1 = *(const bf8*)(Arow + k0 + ska + 8); }
            bf8 bv = *(const bf8*)(Brow + k0 + skb);
            *(bf8*)&As[sra][ska]     = a0;
            *(bf8*)&As[sra][ska + 8] = a1;
            *(bf8*)&Bs[srb][skb]     = bv;
            __syncthreads();
            bf8 af0 = *(const bf8*)&As[wv*32      + fm][fq*8];
            bf8 af1 = *(const bf8*)&As[wv*32 + 16 + fm][fq*8];
            bf8 b0 = *(const bf8*)&Bs[ 0+fm][fq*8];
            bf8 b1 = *(const bf8*)&Bs[16+fm][fq*8];
            bf8 b2 = *(const bf8*)&Bs[32+fm][fq*8];
            bf8 b3 = *(const bf8*)&Bs[48+fm][fq*8];
            acc[0][0] = __builtin_amdgcn_mfma_f32_16x16x32_bf16(af0, b0, acc[0][0], 0,0,0);
            acc[0][1] = __builtin_amdgcn_mfma_f32_16x16x32_bf16(af0, b1, acc[0][1], 0,0,0);
            acc[0][2] = __builtin_amdgcn_mfma_f32_16x16x32_bf16(af0, b2, acc[0][2], 0,0,0);
            acc[0][3] = __builtin_amdgcn_mfma_f32_16x16x32_bf16(af0, b3, acc[0][3], 0,0,0);
            acc[1][0] = __builtin_amdgcn_mfma_f32_16x16x32_bf16(af1, b0, acc[1][0], 0,0,0);
            acc[1][1] = __builtin_amdgcn_mfma_f32_16x16x32_bf16(af1, b1, acc[1][1], 0,0,0);
            acc[1][2] = __builtin_amdgcn_mfma_f32_16x16x32_bf16(af1, b2, acc[1][2], 0,0,0);
            acc[1][3] = __builtin_amdgcn_mfma_f32_16x16x32_bf16(af1, b3, acc[1][3], 0,0,0);
            __syncthreads();
        }
        #pragma unroll
        for (int g = 0; g < 2; g++){
            #pragma unroll
            for (int i = 0; i < 4; i++){
                int row = m0 + wv*32 + g*16 + fq*4 + i;
                if (row >= M) continue;
                u16* dp = dwe_b + (long long)row*512 + n0 + fm;
                dp[ 0] = f2bf(acc[g][0][i]);
                dp[16] = f2bf(acc[g][1][i]);
                dp[32] = f2bf(acc[g][2][i]);
                dp[48] = f2bf(acc[g][3][i]);
            }
        }
        return;
    }
    // ---- expmap0 in-place on the 88 emb rows ----
    {
        float* red = (float*)smem;
        int row = bx - 256;
        float* X = emb_all + (long long)row*512;
        float2 u = *(float2*)(X + t*2);
        red[t] = u.x*u.x + u.y*u.y; __syncthreads();
        for (int s = 128; s > 0; s >>= 1){ if (t < s) red[t] += red[t+s]; __syncthreads(); }
        float f, ome;
        expmap_scale_ome(red[0], &f, &ome);
        *(float2*)(X + t*2) = make_float2(u.x*f, u.y*f);
        if (t == 0) ome_all[row] = ome;
    }
}

// D4: per doc-word row, fused expmap0 + 22 dots -> 1/pdist. One wave per row.
__global__ __launch_bounds__(64)
void k_dots(const u16* __restrict__ dwe_b,
            const float* __restrict__ emb_all, const float* __restrict__ ome_all,
            float* __restrict__ doc_inter, float* __restrict__ sum_inter,
            float* __restrict__ cand_inter)
{
    int row = blockIdx.x;            // b*1019 + l
    int b = row / 1019;
    int l = row - b*1019;
    int lane = threadIdx.x;
    bf8 xr = *(const bf8*)(dwe_b + (long long)row*512 + lane*8);
    float x[8];
    #pragma unroll
    for (int j = 0; j < 8; j++) x[j] = bf2f(((u16*)&xr)[j]);
    float ss = 0.f;
    #pragma unroll
    for (int j = 0; j < 8; j++) ss += x[j]*x[j];
    #pragma unroll
    for (int off = 32; off > 0; off >>= 1) ss += __shfl_xor(ss, off, 64);
    float f, ox;
    expmap_scale_ome(ss, &f, &ox);
    #pragma unroll
    for (int j = 0; j < 8; j++) x[j] *= f;

    for (int c = 0; c < 22; c++){
        int ei = (c == 0) ? b : (c == 1) ? (4 + b) : (8 + b*20 + (c-2));
        const float* y = emb_all + (long long)ei*512 + lane*8;
        float oy = ome_all[ei];
        float4 y0 = *(const float4*)(y);
        float4 y1 = *(const float4*)(y + 4);
        float s = x[0]*y0.x + x[1]*y0.y + x[2]*y0.z + x[3]*y0.w
                + x[4]*y1.x + x[5]*y1.y + x[6]*y1.z + x[7]*y1.w;
        #pragma unroll
        for (int off = 32; off > 0; off >>= 1) s += __shfl_xor(s, off, 64);
        float dist = pdist_stable(ox, oy, s);
        if (lane == 0){
            float inv = 1.0f/fmaxf(dist, 1e-12f);
            if (c == 0) doc_inter[row] = inv;
            else if (c == 1) sum_inter[row] = inv;
            else cand_inter[((long long)(b*20 + (c-2)))*1019 + l] = inv;
        }
    }
}

// D5: blocks 0..79 -> score[b,c]; 80..83 -> summary_score[b]; fp32 out
__global__ __launch_bounds__(256)
void k_final(const float* __restrict__ doc_inter, const float* __restrict__ sum_inter,
             const float* __restrict__ cand_inter,
             const float* __restrict__ emb_all, const float* __restrict__ ome_all,
             float* __restrict__ out)
{
    __shared__ float r0[256], r1[256], r2[256], r3[256];
    int j = blockIdx.x, t = threadIdx.x;
    int b; const float *a, *bb; int xi, yi; int outIdx;
    if (j < 80){
        b = j/20;
        a  = doc_inter + b*1019;
        bb = cand_inter + (long long)j*1019;
        xi = 8 + j; yi = b;
        outIdx = j;
    } else {
        b = j - 80;
        a  = doc_inter + b*1019;
        bb = sum_inter + b*1019;
        xi = 4 + b; yi = b;
        outIdx = 80 + b;
    }
    const float* xe = emb_all + (long long)xi*512;
    const float* ye = emb_all + (long long)yi*512;
    float ox = ome_all[xi], oy = ome_all[yi];
    float saa = 0.f, sbb = 0.f, sab = 0.f, st = 0.f;
    for (int l = t; l < 1019; l += 256){ float av = a[l], bv = bb[l]; saa += av*av; sbb += bv*bv; sab += av*bv; }
    for (int k = t; k < 512; k += 256) st += xe[k]*ye[k];
    r0[t] = saa; r1[t] = sbb; r2[t] = sab; r3[t] = st; __syncthreads();
    for (int s = 128; s > 0; s >>= 1){
        if (t < s){ r0[t] += r0[t+s]; r1[t] += r1[t+s]; r2[t] += r2[t+s]; r3[t] += r3[t+s]; }
        __syncthreads();
    }
    if (t == 0){
        float na = fmaxf(sqrtf(r0[0]), 1e-8f);
        float nb = fmaxf(sqrtf(r1[0]), 1e-8f);
        float cosv = r2[0] / (na*nb);
        float pd = pdist_stable(ox, oy, r3[0]);
        out[outIdx] = -pd*pd + cosv;
    }
}

extern "C" void kernel_launch(void* const* d_in, const int* in_sizes, int n_in,
                              void* d_out, int out_size, void* d_ws, size_t ws_size,
                              hipStream_t stream) {
    const float* text = (const float*)d_in[0];   // (4,512,768) fp32
    const float* summ = (const float*)d_in[1];   // (4,128,768)
    const float* cand = (const float*)d_in[2];   // (4,20,128,768)
    const float* W_d  = (const float*)d_in[3];   // (768,512)
    const float* W_s  = (const float*)d_in[4];
    const float* W_c  = (const float*)d_in[5];
    const float* W_p  = (const float*)d_in[6];   // (512,512)
    const float* cw1  = (const float*)d_in[7];   // (1,768,512)
    const float* cb1  = (const float*)d_in[8];   // (512,)
    const float* cw2  = (const float*)d_in[9];   // (2,768,512) = (1536,512)
    const float* cb2  = (const float*)d_in[10];  // (512,)
    float* out = (float*)d_out;                  // 84 fp32

    const int B = 4, C = 20, H = 768;

    char* base = (char*)d_ws;
    size_t off = 0;
    auto allocF = [&](size_t n)->float*{ float* p = (float*)(base + off); off += ((n*4) + 255) & ~(size_t)255; return p; };
    auto allocU = [&](size_t n)->u16*{ u16* p = (u16*)(base + off); off += ((n*2) + 255) & ~(size_t)255; return p; };

    float* smax = allocF(B*H);
    float* cmax = allocF(B*C*H);
    float* emb_all = allocF(88*512);   // 0..3 doc, 4..7 sum, 8..87 cand
    float* ome_all = allocF(88);
    u16* textb = allocU(4*512*768);
    u16* w1t   = allocU(512*768);
    u16* w2t   = allocU(512*1536);
    u16* wpt   = allocU(512*512);
    u16* gram  = allocU(4076*512);
    u16* dwe_b = allocU(4076*512);     // bf16 raw doc_word pre-emb
    float* doc_inter = allocF(4076);
    float* sum_inter = allocF(4076);
    float* cand_inter= allocF(B*C*1019);

    // D1: rowmax + prep (independent jobs)
    k_stage1<<<3184, 256, 0, stream>>>(summ, cand, text, cw1, cw2, W_p,
                                       smax, cmax, textb, w1t, w2t, wpt);

    // D2: conv MFMA (BM=128) + emb_gemv (independent jobs)
    k_stage2<<<960, 256, 0, stream>>>(textb, w1t, w2t, cb1, cb2,
                                      text, smax, cmax, W_d, W_s, W_c,
                                      gram, emb_all);

    // D3: W_p MFMA (BM=128) + expmap88 (independent jobs)
    k_stage3<<<344, 256, 0, stream>>>(gram, wpt, dwe_b, emb_all, ome_all);

    // D4: fused expmap + pairwise dots -> 1/pdist
    k_dots<<<4076, 64, 0, stream>>>(dwe_b, emb_all, ome_all,
                                    doc_inter, sum_inter, cand_inter);

    // D5: cos_sim reductions + pair pdist -> fp32 outputs
    k_final<<<84, 256, 0, stream>>>(doc_inter, sum_inter, cand_inter,
                                    emb_all, ome_all, out);
}

// Round 10
// 161.054 us; speedup vs baseline: 1.0898x; 1.0898x over previous
//
#include <hip/hip_runtime.h>
#include <math.h>

#define SQRTC  0.94868329805051381f       // sqrt(0.9)
#define MAXN   (0.996f/SQRTC)             // (1-PROJ_EPS)/sqrt(c)
#define OME_CLIP (1.0f - 0.996f*0.996f)   // 1 - c*maxnorm^2
#define TWO_OVER_SQRTC 2.1081851067789197f

typedef unsigned short u16;
typedef __attribute__((ext_vector_type(8))) short bf8;   // 8 bf16 (4 VGPRs)
typedef __attribute__((ext_vector_type(4))) float f4;    // MFMA C/D

__device__ __forceinline__ u16 f2bf(float f){
    union { float f; unsigned int i; } v; v.f = f;
    unsigned int x = v.i;
    unsigned int lsb = (x >> 16) & 1u;
    x += 0x7fffu + lsb;
    return (u16)(x >> 16);
}
__device__ __forceinline__ float bf2f(u16 u){
    union { unsigned int i; float f; } v; v.i = ((unsigned int)u) << 16; return v.f;
}

__device__ __forceinline__ float pdist_stable(float ome_x, float ome_y, float t){
    float u = 1.0f - ome_x, v = 1.0f - ome_y;   // c*x2, c*y2
    float den = fmaxf(1.0f - 1.8f*t + u*v, 1e-15f);
    float q = ome_x*ome_y/den;                   // = 1 - z^2
    q = fminf(fmaxf(q, 2.0e-7f), 1.0f);
    float z = sqrtf(fmaxf(1.0f - q, 0.0f));
    float at = 0.5f * logf((1.0f+z)*(1.0f+z)/q); // atanh(z)
    return TWO_OVER_SQRTC * at;
}

__device__ __forceinline__ void expmap_scale_ome(float sum, float* fout, float* omeout){
    float nraw = sqrtf(fmaxf(sum, 1e-30f));
    float n = fmaxf(nraw, 1e-15f);
    float sn = SQRTC*n;
    float th = tanhf(sn);
    float factor = th/sn;
    float gn = factor*nraw;
    if (gn > MAXN){ *fout = factor*(MAXN/gn); *omeout = OME_CLIP; }
    else { *fout = factor; *omeout = fmaxf((1.0f-th)*(1.0f+th), 1e-12f); }
}

// D1: blocks 0..1007 rowmax; 1008..3183 prep (text cvt + weight transposes).
__global__ __launch_bounds__(256)
void k_stage1(const float* __restrict__ summ, const float* __restrict__ cand,
              const float* __restrict__ text,
              const float* __restrict__ w1, const float* __restrict__ w2,
              const float* __restrict__ wp,
              float* __restrict__ smax, float* __restrict__ cmax,
              u16* __restrict__ textb, u16* __restrict__ w1t,
              u16* __restrict__ w2t, u16* __restrict__ wpt)
{
    __shared__ float shm[1056];
    int bx = blockIdx.x;
    int t = threadIdx.x;
    if (bx < 1008){
        int row = bx / 12, ht = bx - row*12;
        int lane = t & 63, lg = t >> 6;
        int h = ht*64 + lane;
        const float* in = (row < 4) ? (summ + (long long)row*128*768)
                                    : (cand + (long long)(row-4)*128*768);
        const float* p = in + (long long)(lg*32)*768 + h;
        float m = -INFINITY;
        #pragma unroll 8
        for (int l = 0; l < 32; l++) m = fmaxf(m, p[l*768]);
        shm[t] = m; __syncthreads();
        if (t < 64){
            float mm = fmaxf(fmaxf(shm[t], shm[t+64]), fmaxf(shm[t+128], shm[t+192]));
            if (row < 4) smax[row*768 + h] = mm;
            else cmax[(row-4)*768 + h] = mm;
        }
        return;
    }
    int pb = bx - 1008;
    if (pb < 768){
        int base = pb*2048 + t*8;
        float4 a = *(const float4*)(text + base);
        float4 b = *(const float4*)(text + base + 4);
        *(ushort4*)(textb + base)     = make_ushort4(f2bf(a.x), f2bf(a.y), f2bf(a.z), f2bf(a.w));
        *(ushort4*)(textb + base + 4) = make_ushort4(f2bf(b.x), f2bf(b.y), f2bf(b.z), f2bf(b.w));
        return;
    }
    int j = pb - 768;
    const float* in; u16* outp; int K;
    if (j < 384){ in = w1; outp = w1t; K = 768; }
    else if (j < 1152){ j -= 384; in = w2; outp = w2t; K = 1536; }
    else { j -= 1152; in = wp; outp = wpt; K = 512; }
    const int N = 512, ntile = N/32;
    int k0 = (j/ntile)*32, n0 = (j - (j/ntile)*ntile)*32;
    int tx = t & 31, ty = t >> 5;
    #pragma unroll
    for (int i = 0; i < 4; i++)
        shm[(ty*4+i)*33 + tx] = in[(long long)(k0 + ty*4 + i)*N + n0 + tx];
    __syncthreads();
    #pragma unroll
    for (int i = 0; i < 4; i++)
        outp[(long long)(n0 + ty*4 + i)*K + k0 + tx] = f2bf(shm[tx*33 + ty*4+i]);
}

// D2: blocks 0..511 conv MFMA (64x64, round-8 proven); 512..1215 emb_gemv.
__global__ __launch_bounds__(256)
void k_stage2(const u16* __restrict__ textb,
              const u16* __restrict__ w1t, const u16* __restrict__ w2t,
              const float* __restrict__ cb1, const float* __restrict__ cb2,
              const float* __restrict__ text,
              const float* __restrict__ smax, const float* __restrict__ cmax,
              const float* __restrict__ W_d, const float* __restrict__ W_s,
              const float* __restrict__ W_c,
              u16* __restrict__ gram, float* __restrict__ emb_all)
{
    __shared__ char smem[8192];
    int bx = blockIdx.x;
    int t = threadIdx.x;
    if (bx < 512){
        u16 (*As)[32] = (u16(*)[32])smem;
        u16 (*Bs)[32] = (u16(*)[32])(smem + 4096);
        int xx = bx & 63, yy = bx >> 6;
        int job = xx & 1;
        int m0 = (xx >> 1) * 64;
        int n0 = yy * 64;
        int K   = job ? 1536 : 768;
        int M   = job ? 2036 : 2040;
        int rpb = job ? 509 : 510;
        int ob  = job ? 510 : 0;
        const u16* Bt = job ? w2t : w1t;
        const float* bias = job ? cb2 : cb1;
        int sr = t >> 2, sk = (t & 3) << 3;
        const u16* Arow = nullptr;
        { int gm = m0 + sr; if (gm < M){ int b = gm/rpb, l = gm - b*rpb;
            Arow = textb + (long long)b*393216 + (long long)(l+1)*768; } }
        const u16* Brow = Bt + (long long)(n0 + sr)*K;
        int lane = t & 63, wv = t >> 6;
        int fm = lane & 15, fq = lane >> 4;
        int arow = wv*16 + fm;
        f4 acc0 = {0,0,0,0}, acc1 = {0,0,0,0}, acc2 = {0,0,0,0}, acc3 = {0,0,0,0};
        for (int k0 = 0; k0 < K; k0 += 32){
            bf8 av = {};
            if (Arow) av = *(const bf8*)(Arow + k0 + sk);
            bf8 bv = *(const bf8*)(Brow + k0 + sk);
            *(bf8*)&As[sr][sk] = av;
            *(bf8*)&Bs[sr][sk] = bv;
            __syncthreads();
            bf8 af = *(const bf8*)&As[arow][fq*8];
            bf8 b0 = *(const bf8*)&Bs[ 0+fm][fq*8];
            bf8 b1 = *(const bf8*)&Bs[16+fm][fq*8];
            bf8 b2 = *(const bf8*)&Bs[32+fm][fq*8];
            bf8 b3 = *(const bf8*)&Bs[48+fm][fq*8];
            acc0 = __builtin_amdgcn_mfma_f32_16x16x32_bf16(af, b0, acc0, 0, 0, 0);
            acc1 = __builtin_amdgcn_mfma_f32_16x16x32_bf16(af, b1, acc1, 0, 0, 0);
            acc2 = __builtin_amdgcn_mfma_f32_16x16x32_bf16(af, b2, acc2, 0, 0, 0);
            acc3 = __builtin_amdgcn_mfma_f32_16x16x32_bf16(af, b3, acc3, 0, 0, 0);
            __syncthreads();
        }
        int col = n0 + fm;
        float bv0 = bias[col], bv1 = bias[col+16], bv2 = bias[col+32], bv3 = bias[col+48];
        #pragma unroll
        for (int i = 0; i < 4; i++){
            int row = m0 + wv*16 + fq*4 + i;
            if (row >= M) continue;
            int b = row/rpb, l = row - b*rpb;
            long long orow = (long long)b*1019 + ob + l;
            u16* gp = gram + orow*512;
            gp[col]      = f2bf(fmaxf(acc0[i] + bv0, 0.f));
            gp[col + 16] = f2bf(fmaxf(acc1[i] + bv1, 0.f));
            gp[col + 32] = f2bf(fmaxf(acc2[i] + bv2, 0.f));
            gp[col + 48] = f2bf(fmaxf(acc3[i] + bv3, 0.f));
        }
        return;
    }
    // ---- emb_gemv: 88 rows x 8 col-tiles ----
    {
        int eb = bx - 512;
        int row = eb >> 3, nt = eb & 7;
        float* a   = (float*)smem;          // 768 floats
        float* red = (float*)smem + 768;    // 256 floats
        const float* A; const float* W;
        if (row < 4){ A = text + (long long)row*512*768; W = W_d; }
        else if (row < 8){ A = smax + (long long)(row-4)*768; W = W_s; }
        else { A = cmax + (long long)(row-8)*768; W = W_c; }
        for (int k = t; k < 768; k += 256) a[k] = A[k];
        __syncthreads();
        int lane = t & 63, kg = t >> 6;
        int col = nt*64 + lane;
        const float* Wp = W + (long long)(kg*192)*512 + col;
        float acc = 0.f;
        #pragma unroll 8
        for (int k = 0; k < 192; k++) acc += a[kg*192 + k] * Wp[k*512];
        red[t] = acc; __syncthreads();
        if (t < 64) emb_all[(long long)row*512 + col] = red[t] + red[t+64] + red[t+128] + red[t+192];
    }
}

// D3: blocks 0..511 W_p MFMA (64x64, round-8 proven); 512..599 expmap88 (+bf16 copy).
__global__ __launch_bounds__(256)
void k_stage3(const u16* __restrict__ gram, const u16* __restrict__ wpt,
              u16* __restrict__ dwe_b,
              float* __restrict__ emb_all, float* __restrict__ ome_all,
              u16* __restrict__ emb_b)
{
    __shared__ char smem[8192];
    int bx = blockIdx.x;
    int t = threadIdx.x;
    if (bx < 512){
        u16 (*As)[32] = (u16(*)[32])smem;
        u16 (*Bs)[32] = (u16(*)[32])(smem + 4096);
        const int K = 512, M = 4076;
        int m0 = (bx >> 3) * 64;
        int n0 = (bx & 7) * 64;
        int sr = t >> 2, sk = (t & 3) << 3;
        const u16* Arow = (m0 + sr < M) ? (gram + (long long)(m0 + sr)*512) : nullptr;
        const u16* Brow = wpt + (long long)(n0 + sr)*K;
        int lane = t & 63, wv = t >> 6;
        int fm = lane & 15, fq = lane >> 4;
        int arow = wv*16 + fm;
        f4 acc0 = {0,0,0,0}, acc1 = {0,0,0,0}, acc2 = {0,0,0,0}, acc3 = {0,0,0,0};
        for (int k0 = 0; k0 < K; k0 += 32){
            bf8 av = {};
            if (Arow) av = *(const bf8*)(Arow + k0 + sk);
            bf8 bv = *(const bf8*)(Brow + k0 + sk);
            *(bf8*)&As[sr][sk] = av;
            *(bf8*)&Bs[sr][sk] = bv;
            __syncthreads();
            bf8 af = *(const bf8*)&As[arow][fq*8];
            bf8 b0 = *(const bf8*)&Bs[ 0+fm][fq*8];
            bf8 b1 = *(const bf8*)&Bs[16+fm][fq*8];
            bf8 b2 = *(const bf8*)&Bs[32+fm][fq*8];
            bf8 b3 = *(const bf8*)&Bs[48+fm][fq*8];
            acc0 = __builtin_amdgcn_mfma_f32_16x16x32_bf16(af, b0, acc0, 0, 0, 0);
            acc1 = __builtin_amdgcn_mfma_f32_16x16x32_bf16(af, b1, acc1, 0, 0, 0);
            acc2 = __builtin_amdgcn_mfma_f32_16x16x32_bf16(af, b2, acc2, 0, 0, 0);
            acc3 = __builtin_amdgcn_mfma_f32_16x16x32_bf16(af, b3, acc3, 0, 0, 0);
            __syncthreads();
        }
        int col = n0 + fm;
        #pragma unroll
        for (int i = 0; i < 4; i++){
            int row = m0 + wv*16 + fq*4 + i;
            if (row >= M) continue;
            u16* dp = dwe_b + (long long)row*512;
            dp[col]      = f2bf(acc0[i]);
            dp[col + 16] = f2bf(acc1[i]);
            dp[col + 32] = f2bf(acc2[i]);
            dp[col + 48] = f2bf(acc3[i]);
        }
        return;
    }
    // ---- expmap0 in-place on the 88 emb rows; also emit bf16 copy ----
    {
        float* red = (float*)smem;
        int row = bx - 512;
        float* X = emb_all + (long long)row*512;
        float2 u = *(float2*)(X + t*2);
        red[t] = u.x*u.x + u.y*u.y; __syncthreads();
        for (int s = 128; s > 0; s >>= 1){ if (t < s) red[t] += red[t+s]; __syncthreads(); }
        float f, ome;
        expmap_scale_ome(red[0], &f, &ome);
        float sx = u.x*f, sy = u.y*f;
        *(float2*)(X + t*2) = make_float2(sx, sy);
        u16* Xb = emb_b + (long long)row*512;
        Xb[t*2]   = f2bf(sx);
        Xb[t*2+1] = f2bf(sy);
        if (t == 0) ome_all[row] = ome;
    }
}

// D4: MFMA dots. T[l,c] = dwe_raw . emb_scaled; per-row ss accumulated during
// A-staging; epilogue = expmap scale + pdist elementwise. 4 batches x 16 m-tiles.
__global__ __launch_bounds__(256)
void k_dots_mfma(const u16* __restrict__ dwe_b, const u16* __restrict__ emb_b,
                 const float* __restrict__ ome_all,
                 float* __restrict__ doc_inter, float* __restrict__ sum_inter,
                 float* __restrict__ cand_inter)
{
    __shared__ u16 As[64][32];
    __shared__ u16 Bs[32][32];
    __shared__ float ssp[64][4];
    __shared__ float ssl[64];
    __shared__ float oyl[22];
    int bx = blockIdx.x;
    int b  = bx >> 4;          // batch
    int m0 = (bx & 15) * 64;   // row tile within batch (1019 rows)
    int t = threadIdx.x;
    int sra = t >> 2, ska = (t & 3) << 3;
    const u16* Arow = (m0 + sra < 1019) ? (dwe_b + (long long)(b*1019 + m0 + sra)*512) : nullptr;
    const u16* Brow = nullptr;
    if (t < 128){
        int n = t >> 2;        // 0..31
        if (n < 22){
            int ei = (n == 0) ? b : (n == 1) ? 4 + b : 8 + b*20 + (n - 2);
            Brow = emb_b + (long long)ei*512;
        }
    }
    if (t < 22) oyl[t] = ome_all[(t == 0) ? b : (t == 1) ? 4 + b : 8 + b*20 + (t - 2)];
    int lane = t & 63, wv = t >> 6;
    int fm = lane & 15, fq = lane >> 4;
    f4 acc0 = {0,0,0,0}, acc1 = {0,0,0,0};
    float ssq = 0.f;
    for (int k0 = 0; k0 < 512; k0 += 32){
        bf8 av = {};
        if (Arow) av = *(const bf8*)(Arow + k0 + ska);
        *(bf8*)&As[sra][ska] = av;
        if (t < 128){
            bf8 bv = {};
            if (Brow) bv = *(const bf8*)(Brow + k0 + ((t & 3) << 3));
            *(bf8*)&Bs[t >> 2][(t & 3) << 3] = bv;
        }
        #pragma unroll
        for (int j = 0; j < 8; j++){ float x = bf2f(((u16*)&av)[j]); ssq += x*x; }
        __syncthreads();
        bf8 af = *(const bf8*)&As[wv*16 + fm][fq*8];
        bf8 b0 = *(const bf8*)&Bs[fm][fq*8];
        bf8 b1 = *(const bf8*)&Bs[16 + fm][fq*8];
        acc0 = __builtin_amdgcn_mfma_f32_16x16x32_bf16(af, b0, acc0, 0, 0, 0);
        acc1 = __builtin_amdgcn_mfma_f32_16x16x32_bf16(af, b1, acc1, 0, 0, 0);
        __syncthreads();
    }
    ssp[sra][t & 3] = ssq; __syncthreads();
    if (t < 64) ssl[t] = ssp[t][0] + ssp[t][1] + ssp[t][2] + ssp[t][3];
    __syncthreads();
    #pragma unroll
    for (int i = 0; i < 4; i++){
        int rtile = wv*16 + fq*4 + i;
        int row = m0 + rtile;
        if (row >= 1019) continue;
        float f, ox;
        expmap_scale_ome(ssl[rtile], &f, &ox);
        long long grow = (long long)b*1019 + row;
        #pragma unroll
        for (int g = 0; g < 2; g++){
            int c = g*16 + fm;
            if (c >= 22) continue;
            float s = (g ? acc1[i] : acc0[i]) * f;
            float dist = pdist_stable(ox, oyl[c], s);
            float inv = 1.0f/fmaxf(dist, 1e-12f);
            if (c == 0) doc_inter[grow] = inv;
            else if (c == 1) sum_inter[grow] = inv;
            else cand_inter[((long long)(b*20 + (c - 2)))*1019 + row] = inv;
        }
    }
}

// D5: blocks 0..79 -> score[b,c]; 80..83 -> summary_score[b]; fp32 out
__global__ __launch_bounds__(256)
void k_final(const float* __restrict__ doc_inter, const float* __restrict__ sum_inter,
             const float* __restrict__ cand_inter,
             const float* __restrict__ emb_all, const float* __restrict__ ome_all,
             float* __restrict__ out)
{
    __shared__ float r0[256], r1[256], r2[256], r3[256];
    int j = blockIdx.x, t = threadIdx.x;
    int b; const float *a, *bb; int xi, yi; int outIdx;
    if (j < 80){
        b = j/20;
        a  = doc_inter + b*1019;
        bb = cand_inter + (long long)j*1019;
        xi = 8 + j; yi = b;
        outIdx = j;
    } else {
        b = j - 80;
        a  = doc_inter + b*1019;
        bb = sum_inter + b*1019;
        xi = 4 + b; yi = b;
        outIdx = 80 + b;
    }
    const float* xe = emb_all + (long long)xi*512;
    const float* ye = emb_all + (long long)yi*512;
    float ox = ome_all[xi], oy = ome_all[yi];
    float saa = 0.f, sbb = 0.f, sab = 0.f, st = 0.f;
    for (int l = t; l < 1019; l += 256){ float av = a[l], bv = bb[l]; saa += av*av; sbb += bv*bv; sab += av*bv; }
    for (int k = t; k < 512; k += 256) st += xe[k]*ye[k];
    r0[t] = saa; r1[t] = sbb; r2[t] = sab; r3[t] = st; __syncthreads();
    for (int s = 128; s > 0; s >>= 1){
        if (t < s){ r0[t] += r0[t+s]; r1[t] += r1[t+s]; r2[t] += r2[t+s]; r3[t] += r3[t+s]; }
        __syncthreads();
    }
    if (t == 0){
        float na = fmaxf(sqrtf(r0[0]), 1e-8f);
        float nb = fmaxf(sqrtf(r1[0]), 1e-8f);
        float cosv = r2[0] / (na*nb);
        float pd = pdist_stable(ox, oy, r3[0]);
        out[outIdx] = -pd*pd + cosv;
    }
}

extern "C" void kernel_launch(void* const* d_in, const int* in_sizes, int n_in,
                              void* d_out, int out_size, void* d_ws, size_t ws_size,
                              hipStream_t stream) {
    const float* text = (const float*)d_in[0];   // (4,512,768) fp32
    const float* summ = (const float*)d_in[1];   // (4,128,768)
    const float* cand = (const float*)d_in[2];   // (4,20,128,768)
    const float* W_d  = (const float*)d_in[3];   // (768,512)
    const float* W_s  = (const float*)d_in[4];
    const float* W_c  = (const float*)d_in[5];
    const float* W_p  = (const float*)d_in[6];   // (512,512)
    const float* cw1  = (const float*)d_in[7];   // (1,768,512)
    const float* cb1  = (const float*)d_in[8];   // (512,)
    const float* cw2  = (const float*)d_in[9];   // (2,768,512) = (1536,512)
    const float* cb2  = (const float*)d_in[10];  // (512,)
    float* out = (float*)d_out;                  // 84 fp32

    const int B = 4, C = 20, H = 768;

    char* base = (char*)d_ws;
    size_t off = 0;
    auto allocF = [&](size_t n)->float*{ float* p = (float*)(base + off); off += ((n*4) + 255) & ~(size_t)255; return p; };
    auto allocU = [&](size_t n)->u16*{ u16* p = (u16*)(base + off); off += ((n*2) + 255) & ~(size_t)255; return p; };

    float* smax = allocF(B*H);
    float* cmax = allocF(B*C*H);
    float* emb_all = allocF(88*512);   // 0..3 doc, 4..7 sum, 8..87 cand
    float* ome_all = allocF(88);
    u16* emb_b = allocU(88*512);       // bf16 copy of scaled embeddings
    u16* textb = allocU(4*512*768);
    u16* w1t   = allocU(512*768);
    u16* w2t   = allocU(512*1536);
    u16* wpt   = allocU(512*512);
    u16* gram  = allocU(4076*512);
    u16* dwe_b = allocU(4076*512);     // bf16 raw doc_word pre-emb
    float* doc_inter = allocF(4076);
    float* sum_inter = allocF(4076);
    float* cand_inter= allocF(B*C*1019);

    // D1: rowmax + prep (independent jobs)
    k_stage1<<<3184, 256, 0, stream>>>(summ, cand, text, cw1, cw2, W_p,
                                       smax, cmax, textb, w1t, w2t, wpt);

    // D2: conv MFMA (64x64) + emb_gemv (independent jobs)
    k_stage2<<<1216, 256, 0, stream>>>(textb, w1t, w2t, cb1, cb2,
                                       text, smax, cmax, W_d, W_s, W_c,
                                       gram, emb_all);

    // D3: W_p MFMA (64x64) + expmap88/bf16-copy (independent jobs)
    k_stage3<<<600, 256, 0, stream>>>(gram, wpt, dwe_b, emb_all, ome_all, emb_b);

    // D4: MFMA dots (T = dwe.emb^T) + fused expmap/pdist epilogue
    k_dots_mfma<<<64, 256, 0, stream>>>(dwe_b, emb_b, ome_all,
                                        doc_inter, sum_inter, cand_inter);

    // D5: cos_sim reductions + pair pdist -> fp32 outputs
    k_final<<<84, 256, 0, stream>>>(doc_inter, sum_inter, cand_inter,
                                    emb_all, ome_all, out);
}